// Round 3
// baseline (159.759 us; speedup 1.0000x reference)
//
#include <hip/hip_runtime.h>
#include <hip/hip_bf16.h>
#include <stdint.h>

// ---------------------------------------------------------------------------
// MaskedPolicy: obs->MLP->heads (masked log-softmax, gather, entropy) + critic
// B=8192 OBS=512 HID=1024 N*SUM=2560 (+512 critic cols = 3072 fused GEMM3)
// GEMMs: m201-style 256x256xBK64 8-phase, counted vmcnt, st_16x32 LDS swizzle.
// ---------------------------------------------------------------------------

typedef __bf16 v8bf __attribute__((ext_vector_type(8)));
typedef float  v4f  __attribute__((ext_vector_type(4)));

__device__ __forceinline__ void load_lds16(const void* g, void* l) {
  auto gp = (const __attribute__((address_space(1))) char*)(uintptr_t)g;
  auto lp = (__attribute__((address_space(3))) char*)(uintptr_t)l;
  __builtin_amdgcn_global_load_lds(gp, lp, 16, 0, 0);
}

// ---------------------------------------------------------------------------
// prep kernels (unchanged, verified)
// ---------------------------------------------------------------------------

__global__ void convert_obs(const float4* __restrict__ in, int4* __restrict__ out, int n8) {
  const int i = blockIdx.x * blockDim.x + threadIdx.x;
  if (i >= n8) return;
  const float4 x = in[i * 2], y = in[i * 2 + 1];
  union { __hip_bfloat16 h[8]; int4 v; } u;
  u.h[0] = __float2bfloat16(x.x);
  u.h[1] = __float2bfloat16(x.y);
  u.h[2] = __float2bfloat16(x.z);
  u.h[3] = __float2bfloat16(x.w);
  u.h[4] = __float2bfloat16(y.x);
  u.h[5] = __float2bfloat16(y.y);
  u.h[6] = __float2bfloat16(y.z);
  u.h[7] = __float2bfloat16(y.w);
  out[i] = u.v;
}

__global__ void build_bias(const float* __restrict__ headsb, const float* __restrict__ bc1,
                           float* __restrict__ biasc) {
  const int i = blockIdx.x * blockDim.x + threadIdx.x;
  if (i < 2560) biasc[i] = headsb[i];
  else if (i < 3072) biasc[i] = bc1[i - 2560];
}

__global__ void transpose_to_bf16(const float* __restrict__ in, __hip_bfloat16* __restrict__ out,
                                  int R, int C) {
  __shared__ float t[32][33];
  const int bx = blockIdx.x * 32, by = blockIdx.y * 32;
  in  += (size_t)blockIdx.z * R * C;
  out += (size_t)blockIdx.z * R * C;
  const int x = threadIdx.x, y = threadIdx.y;
#pragma unroll
  for (int i = 0; i < 32; i += 8)
    t[y + i][x] = in[(size_t)(by + y + i) * C + bx + x];
  __syncthreads();
#pragma unroll
  for (int i = 0; i < 32; i += 8)
    out[(size_t)(bx + y + i) * R + by + x] = __float2bfloat16(t[x][y + i]);
}

// ---------------------------------------------------------------------------
// 8-phase 256x256 GEMM: C = relu?(A[M][K] * Bt[N][K]^T + bias[N]) -> bf16
// 512 thr (8 waves, 2Mx4N), BK=64, LDS 128KiB (2 dbuf x {A0,A1,B0,B1} x 16KiB)
// half-tile layout: 16x32-elem subtiles, inner stride 64B, swz byte^=((b>>9)&1)<<5
// ---------------------------------------------------------------------------

__device__ __forceinline__ void rd_a(v8bf (&a)[4][2], const char* base, int mbase) {
#pragma unroll
  for (int m = 0; m < 4; ++m)
#pragma unroll
    for (int ks = 0; ks < 2; ++ks)
      a[m][ks] = *(const v8bf*)(base + (((mbase + m) * 2 + ks) << 10));
}

__device__ __forceinline__ void rd_b2(v8bf (&b)[4][2], const char* base, int n0) {
#pragma unroll
  for (int n = 0; n < 2; ++n)
#pragma unroll
    for (int ks = 0; ks < 2; ++ks)
      b[n0 + n][ks] = *(const v8bf*)(base + (((n0 + n) * 2 + ks) << 10));
}

template<int M0, int N0>
__device__ __forceinline__ void mfma_quad(v4f (&acc)[8][4], const v8bf (&a)[4][2],
                                          const v8bf (&b)[4][2]) {
#pragma unroll
  for (int m = 0; m < 4; ++m)
#pragma unroll
    for (int n = 0; n < 2; ++n)
#pragma unroll
      for (int ks = 0; ks < 2; ++ks)
        acc[M0 + m][N0 + n] =
            __builtin_amdgcn_mfma_f32_16x16x32_bf16(a[m][ks], b[N0 + n][ks],
                                                    acc[M0 + m][N0 + n], 0, 0, 0);
}

#define BARRIER __builtin_amdgcn_s_barrier()
#define SCHEDB  __builtin_amdgcn_sched_barrier(0)
#define WAIT_LGKM0 do { asm volatile("s_waitcnt lgkmcnt(0)" ::: "memory"); SCHEDB; } while (0)
#define WAIT_VM2   do { asm volatile("s_waitcnt vmcnt(2)" ::: "memory"); SCHEDB; } while (0)
#define WAIT_VM0   do { asm volatile("s_waitcnt vmcnt(0)" ::: "memory"); SCHEDB; } while (0)

#define MFMA_PH(Q) do { __builtin_amdgcn_s_setprio(1); Q; __builtin_amdgcn_s_setprio(0); SCHEDB; } while (0)

// stage macros: linear LDS dest (dbuf db), advance source 128B per K-tile
#define ST_A0(db) { load_lds16(pA0a, s0 + ((db) << 16));          load_lds16(pA0b, s0 + ((db) << 16) + 8192);  pA0a += 128; pA0b += 128; }
#define ST_A1(db) { load_lds16(pA1a, s0 + ((db) << 16) + 16384);  load_lds16(pA1b, s0 + ((db) << 16) + 24576); pA1a += 128; pA1b += 128; }
#define ST_B0(db) { load_lds16(pB0a, s0 + ((db) << 16) + 32768);  load_lds16(pB0b, s0 + ((db) << 16) + 40960); pB0a += 128; pB0b += 128; }
#define ST_B1(db) { load_lds16(pB1a, s0 + ((db) << 16) + 49152);  load_lds16(pB1b, s0 + ((db) << 16) + 57344); pB1a += 128; pB1b += 128; }

__global__ __launch_bounds__(512, 2)
void gemm_8ph(const __hip_bfloat16* __restrict__ A,
              const __hip_bfloat16* __restrict__ Bt,
              const float* __restrict__ bias,
              __hip_bfloat16* __restrict__ C,
              int M, int N, int K, int relu_from, int gx) {
  __shared__ char smem[131072];

  const int tid  = threadIdx.x;
  const int lane = tid & 63;
  const int wave = tid >> 6;
  const int wr = wave >> 2;        // 0..1  (M half)
  const int wc = wave & 3;         // 0..3  (N quarter)
  const int lr = lane & 15, ls = lane >> 4;

  // bijective XCD swizzle (nwg % 8 == 0 for all our grids)
  const int nwg = gridDim.x;
  const int q8 = nwg >> 3;
  const int id = (blockIdx.x & 7) * q8 + (blockIdx.x >> 3);
  const int bx = id % gx, by = id / gx;
  const int m0 = by * 256, n0 = bx * 256;

  // --- staging source decode: chunk q holds element (row,col) with
  //     swz(layout(row,col)) == q*16; swz is an involution -> decode swz(q*16)
  const int o0 = tid << 4;
  const int s_0 = o0 ^ (((o0 >> 9) & 1) << 5);
  const int r0 = ((s_0 >> 10) >> 1) * 16 + ((s_0 >> 6) & 15);
  const int cb0 = (((((s_0 >> 10) & 1) << 2) | ((s_0 >> 4) & 3)) << 4);
  const int o1 = (tid + 512) << 4;
  const int s_1 = o1 ^ (((o1 >> 9) & 1) << 5);
  const int r1 = ((s_1 >> 10) >> 1) * 16 + ((s_1 >> 6) & 15);
  const int cb1 = (((((s_1 >> 10) & 1) << 2) | ((s_1 >> 4) & 3)) << 4);

  const size_t K2 = (size_t)K * 2;
  const char* pA0a = (const char*)A + (size_t)(m0 +       r0) * K2 + cb0;
  const char* pA0b = (const char*)A + (size_t)(m0 +       r1) * K2 + cb1;
  const char* pA1a = (const char*)A + (size_t)(m0 + 128 + r0) * K2 + cb0;
  const char* pA1b = (const char*)A + (size_t)(m0 + 128 + r1) * K2 + cb1;
  const char* pB0a = (const char*)Bt + (size_t)(n0 +       r0) * K2 + cb0;
  const char* pB0b = (const char*)Bt + (size_t)(n0 +       r1) * K2 + cb1;
  const char* pB1a = (const char*)Bt + (size_t)(n0 + 128 + r0) * K2 + cb0;
  const char* pB1b = (const char*)Bt + (size_t)(n0 + 128 + r1) * K2 + cb1;

  char* const s0 = smem + (tid << 4);

  // --- reader bases (swizzled): byte = subtile<<10 + lr*64 + (ls*16 ^ ((lr&8)<<2))
  const int laneOff = lr * 64 + ((ls * 16) ^ ((lr & 8) << 2));
  const char* aB0 = smem + wr * 16384 + laneOff;
  const char* bB0 = smem + 32768 + (wc >> 1) * 16384 + (wc & 1) * 8192 + laneOff;
  const char* aB1 = aB0 + 65536;
  const char* bB1 = bB0 + 65536;

  v4f acc[8][4] = {};
  v8bf aLo[4][2], aHi[4][2], bFr[4][2];

  // --- prologue: stage tile0 (dbuf0) fully + tile1.A0; gate; barrier
  ST_A0(0); ST_A1(0); ST_B0(0); ST_B1(0);
  ST_A0(1);
  WAIT_VM2;
  BARRIER; SCHEDB;

  const int NI = (K >> 7) - 1;   // NT/2 - 1 full iterations (NT = K/64, even)
  for (int i = 0; i < NI; ++i) {
    // ---- tile 2i (dbuf0) ----
    // p1
    rd_a(aLo, aB0, 0); rd_b2(bFr, bB0, 0);
    ST_A1(1);
    BARRIER; WAIT_LGKM0;
    MFMA_PH((mfma_quad<0, 0>(acc, aLo, bFr)));
    BARRIER;
    // p2
    rd_b2(bFr, bB0, 2);
    ST_B0(1);
    BARRIER; WAIT_LGKM0;
    MFMA_PH((mfma_quad<0, 2>(acc, aLo, bFr)));
    BARRIER;
    // p3
    rd_a(aHi, aB0, 4);
    ST_B1(1);
    BARRIER; WAIT_LGKM0;
    MFMA_PH((mfma_quad<4, 2>(acc, aHi, bFr)));
    BARRIER;
    // p4
    ST_A0(0);
    WAIT_VM2;
    BARRIER;
    MFMA_PH((mfma_quad<4, 0>(acc, aHi, bFr)));
    BARRIER;
    // ---- tile 2i+1 (dbuf1) ----
    // p5
    rd_a(aLo, aB1, 0); rd_b2(bFr, bB1, 0);
    ST_A1(0);
    BARRIER; WAIT_LGKM0;
    MFMA_PH((mfma_quad<0, 0>(acc, aLo, bFr)));
    BARRIER;
    // p6
    rd_b2(bFr, bB1, 2);
    ST_B0(0);
    BARRIER; WAIT_LGKM0;
    MFMA_PH((mfma_quad<0, 2>(acc, aLo, bFr)));
    BARRIER;
    // p7
    rd_a(aHi, aB1, 4);
    ST_B1(0);
    BARRIER; WAIT_LGKM0;
    MFMA_PH((mfma_quad<4, 2>(acc, aHi, bFr)));
    BARRIER;
    // p8
    ST_A0(1);
    WAIT_VM2;
    BARRIER;
    MFMA_PH((mfma_quad<4, 0>(acc, aHi, bFr)));
    BARRIER;
  }

  // ---- epilogue pair: tiles NT-2 (dbuf0), NT-1 (dbuf1) ----
  // p1
  rd_a(aLo, aB0, 0); rd_b2(bFr, bB0, 0);
  ST_A1(1);
  BARRIER; WAIT_LGKM0;
  MFMA_PH((mfma_quad<0, 0>(acc, aLo, bFr)));
  BARRIER;
  // p2
  rd_b2(bFr, bB0, 2);
  ST_B0(1);
  BARRIER; WAIT_LGKM0;
  MFMA_PH((mfma_quad<0, 2>(acc, aLo, bFr)));
  BARRIER;
  // p3
  rd_a(aHi, aB0, 4);
  ST_B1(1);
  BARRIER; WAIT_LGKM0;
  MFMA_PH((mfma_quad<4, 2>(acc, aHi, bFr)));
  BARRIER;
  // p4 — drain all remaining stages (last tile now resident)
  WAIT_VM0;
  BARRIER;
  MFMA_PH((mfma_quad<4, 0>(acc, aHi, bFr)));
  BARRIER;
  // p5
  rd_a(aLo, aB1, 0); rd_b2(bFr, bB1, 0);
  BARRIER; WAIT_LGKM0;
  MFMA_PH((mfma_quad<0, 0>(acc, aLo, bFr)));
  BARRIER;
  // p6
  rd_b2(bFr, bB1, 2);
  BARRIER; WAIT_LGKM0;
  MFMA_PH((mfma_quad<0, 2>(acc, aLo, bFr)));
  BARRIER;
  // p7
  rd_a(aHi, aB1, 4);
  BARRIER; WAIT_LGKM0;
  MFMA_PH((mfma_quad<4, 2>(acc, aHi, bFr)));
  // p8 (no LDS reuse after this — no barriers needed)
  MFMA_PH((mfma_quad<4, 0>(acc, aHi, bFr)));

  // --- epilogue: C/D layout col=lane&15, row=(lane>>4)*4+reg  [m89-verified]
  const int colb = n0 + wc * 64 + lr;
  const int rowb = m0 + wr * 128 + ls * 4;
#pragma unroll
  for (int n = 0; n < 4; ++n) {
    const int col = colb + n * 16;
    const float bv = bias[col];
    const bool rl = (col >= relu_from);
#pragma unroll
    for (int m = 0; m < 8; ++m) {
      const int rbase = rowb + m * 16;
#pragma unroll
      for (int j = 0; j < 4; ++j) {
        float v = acc[m][n][j] + bv;
        if (rl) v = fmaxf(v, 0.0f);
        C[(size_t)(rbase + j) * N + col] = __float2bfloat16(v);
      }
    }
  }
}

// ---------------------------------------------------------------------------
// finalize (unchanged, verified): wave per row, 8 segments/pass, vector loads
// ---------------------------------------------------------------------------

__global__ __launch_bounds__(256)
void finalize_kernel(const __hip_bfloat16* __restrict__ out3,
                     const int* __restrict__ masks,
                     const int* __restrict__ actions,
                     const float* __restrict__ Wc2,
                     const float* __restrict__ bc2,
                     float* __restrict__ out) {
  const int lane = threadIdx.x & 63;
  const int r = blockIdx.x * 4 + (threadIdx.x >> 6);
  const __hip_bfloat16* row = out3 + (size_t)r * 3072;
  const int* mrow = masks + (size_t)r * 2560;
  const int* arow = actions + r * 40;

  const int g = lane >> 3;

  float lp_sum = 0.f, ent_sum = 0.f;

#pragma unroll
  for (int p = 0; p < 5; ++p) {
    const int base = p * 512 + lane * 8;
    union { int4 q; __hip_bfloat16 h[8]; } u;
    u.q = *(const int4*)(row + base);
    const int4 ma = *(const int4*)(mrow + base);
    const int4 mb = *(const int4*)(mrow + base + 4);

    float v[8];
    v[0] = ma.x ? __bfloat162float(u.h[0]) : -1.0e9f;
    v[1] = ma.y ? __bfloat162float(u.h[1]) : -1.0e9f;
    v[2] = ma.z ? __bfloat162float(u.h[2]) : -1.0e9f;
    v[3] = ma.w ? __bfloat162float(u.h[3]) : -1.0e9f;
    v[4] = mb.x ? __bfloat162float(u.h[4]) : -1.0e9f;
    v[5] = mb.y ? __bfloat162float(u.h[5]) : -1.0e9f;
    v[6] = mb.z ? __bfloat162float(u.h[6]) : -1.0e9f;
    v[7] = mb.w ? __bfloat162float(u.h[7]) : -1.0e9f;

    float mx = fmaxf(fmaxf(fmaxf(v[0], v[1]), fmaxf(v[2], v[3])),
                     fmaxf(fmaxf(v[4], v[5]), fmaxf(v[6], v[7])));
#pragma unroll
    for (int o = 1; o < 8; o <<= 1) mx = fmaxf(mx, __shfl_xor(mx, o));

    float s = 0.f, sv = 0.f;
#pragma unroll
    for (int j = 0; j < 8; ++j) {
      const float e = __expf(v[j] - mx);
      s += e;
      sv += e * v[j];
    }
#pragma unroll
    for (int o = 1; o < 8; o <<= 1) { s += __shfl_xor(s, o); sv += __shfl_xor(sv, o); }

    const float logZ = __logf(s) + mx;

    const int act = arow[p * 8 + g];
    float va_loc = v[0];
#pragma unroll
    for (int j = 1; j < 8; ++j) va_loc = ((act & 7) == j) ? v[j] : va_loc;
    const float va = __shfl(va_loc, (lane & 56) | ((act >> 3) & 7));

    if ((unsigned)act < 64u) {
      lp_sum += va - logZ;
      ent_sum += logZ - sv / s;
    } else {
      lp_sum += -1000.0f;
    }
  }

#pragma unroll
  for (int o = 8; o < 64; o <<= 1) {
    lp_sum += __shfl_xor(lp_sum, o);
    ent_sum += __shfl_xor(ent_sum, o);
  }

  union { int4 q; __hip_bfloat16 h[8]; } c;
  c.q = *(const int4*)(row + 2560 + lane * 8);
  const float4 w0 = *(const float4*)(Wc2 + lane * 8);
  const float4 w1 = *(const float4*)(Wc2 + lane * 8 + 4);
  float acc = __bfloat162float(c.h[0]) * w0.x + __bfloat162float(c.h[1]) * w0.y +
              __bfloat162float(c.h[2]) * w0.z + __bfloat162float(c.h[3]) * w0.w +
              __bfloat162float(c.h[4]) * w1.x + __bfloat162float(c.h[5]) * w1.y +
              __bfloat162float(c.h[6]) * w1.z + __bfloat162float(c.h[7]) * w1.w;
#pragma unroll
  for (int o = 32; o > 0; o >>= 1) acc += __shfl_xor(acc, o);

  if (lane == 0) {
    out[r]         = lp_sum;
    out[8192 + r]  = ent_sum;
    out[16384 + r] = acc + bc2[0];
  }
}

// ---------------------------------------------------------------------------

extern "C" void kernel_launch(void* const* d_in, const int* in_sizes, int n_in,
                              void* d_out, int out_size, void* d_ws, size_t ws_size,
                              hipStream_t stream) {
  const float* obs    = (const float*)d_in[0];
  const int*   actions= (const int*)d_in[1];
  const int*   masks  = (const int*)d_in[2];
  const float* W1     = (const float*)d_in[3];
  const float* b1     = (const float*)d_in[4];
  const float* W2     = (const float*)d_in[5];
  const float* b2     = (const float*)d_in[6];
  const float* headsW = (const float*)d_in[7];
  const float* headsb = (const float*)d_in[8];
  const float* Wc1    = (const float*)d_in[9];
  const float* bc1    = (const float*)d_in[10];
  const float* Wc2    = (const float*)d_in[11];
  const float* bc2    = (const float*)d_in[12];
  float* out = (float*)d_out;

  char* ws = (char*)d_ws;
  __hip_bfloat16* obsB  = (__hip_bfloat16*)(ws);              // 8192*512*2   = 8388608
  __hip_bfloat16* W1t   = (__hip_bfloat16*)(ws + 8388608);    // 1024*512*2   = 1048576
  __hip_bfloat16* W2t   = (__hip_bfloat16*)(ws + 9437184);    // 1024*1024*2  = 2097152
  __hip_bfloat16* Wbigt = (__hip_bfloat16*)(ws + 11534336);   // 3072*1024*2  = 6291456
  float*          biasc = (float*)(ws + 17825792);            // 3072*4       = 12288
  __hip_bfloat16* h1    = (__hip_bfloat16*)(ws + 17838080);   // 8192*1024*2  = 16777216
  __hip_bfloat16* h2    = (__hip_bfloat16*)(ws + 34615296);   // 8192*1024*2  = 16777216
  __hip_bfloat16* out3  = (__hip_bfloat16*)(ws + 51392512);   // 8192*3072*2  = 50331648

  convert_obs<<<2048, 256, 0, stream>>>((const float4*)obs, (int4*)obsB, 524288);
  build_bias<<<12, 256, 0, stream>>>(headsb, bc1, biasc);
  transpose_to_bf16<<<dim3(32, 16, 1), dim3(32, 8), 0, stream>>>(W1, W1t, 512, 1024);
  transpose_to_bf16<<<dim3(32, 32, 1), dim3(32, 8), 0, stream>>>(W2, W2t, 1024, 1024);
  transpose_to_bf16<<<dim3(10, 32, 8), dim3(32, 8), 0, stream>>>(headsW, Wbigt, 1024, 320);
  transpose_to_bf16<<<dim3(16, 32, 1), dim3(32, 8), 0, stream>>>(Wc1, Wbigt + 2560 * 1024, 1024, 512);

  // 8-phase 256^2 GEMMs: grids 32x4=128, 32x4=128, 32x12=384 (all %8==0)
  gemm_8ph<<<dim3(128), 512, 0, stream>>>(obsB, W1t, b1, h1, 8192, 1024, 512, 0, 4);
  gemm_8ph<<<dim3(128), 512, 0, stream>>>(h1, W2t, b2, h2, 8192, 1024, 1024, 0, 4);
  gemm_8ph<<<dim3(384), 512, 0, stream>>>(h2, Wbigt, biasc, out3, 8192, 3072, 1024, 2560, 12);

  finalize_kernel<<<2048, 256, 0, stream>>>(out3, masks, actions, Wc2, bc2, out);
}

// Round 4
// 150.333 us; speedup vs baseline: 1.0627x; 1.0627x over previous
//
#include <hip/hip_runtime.h>
#include <hip/hip_bf16.h>
#include <stdint.h>

// ---------------------------------------------------------------------------
// MaskedPolicy: obs->MLP->heads (masked log-softmax, gather, entropy) + critic
// B=8192 OBS=512 HID=1024 N*SUM=2560 (+512 critic cols = 3072 fused GEMM3)
// GEMM: BK=32, 4-deep K-tile LDS ring, counted vmcnt(8/6) gates (3-tile
// prefetch depth), per-phase {ds_read | stage | barrier | lgkm0 | 16 MFMA}.
// ---------------------------------------------------------------------------

typedef __bf16 v8bf __attribute__((ext_vector_type(8)));
typedef float  v4f  __attribute__((ext_vector_type(4)));

__device__ __forceinline__ void load_lds16(const void* g, void* l) {
  auto gp = (const __attribute__((address_space(1))) char*)(uintptr_t)g;
  auto lp = (__attribute__((address_space(3))) char*)(uintptr_t)l;
  __builtin_amdgcn_global_load_lds(gp, lp, 16, 0, 0);
}

#define BARRIER __builtin_amdgcn_s_barrier()
#define SCHEDB  __builtin_amdgcn_sched_barrier(0)
#define WAIT_LGKM0 do { asm volatile("s_waitcnt lgkmcnt(0)" ::: "memory"); SCHEDB; } while (0)

template<int N>
__device__ __forceinline__ void wait_vm() {
  if constexpr (N == 8)      asm volatile("s_waitcnt vmcnt(8)" ::: "memory");
  else if constexpr (N == 6) asm volatile("s_waitcnt vmcnt(6)" ::: "memory");
  else if constexpr (N == 4) asm volatile("s_waitcnt vmcnt(4)" ::: "memory");
  else if constexpr (N == 3) asm volatile("s_waitcnt vmcnt(3)" ::: "memory");
  else                       asm volatile("s_waitcnt vmcnt(0)" ::: "memory");
  SCHEDB;
}

// ---------------------------------------------------------------------------
// prep kernels (unchanged, verified)
// ---------------------------------------------------------------------------

__global__ void convert_obs(const float4* __restrict__ in, int4* __restrict__ out, int n8) {
  const int i = blockIdx.x * blockDim.x + threadIdx.x;
  if (i >= n8) return;
  const float4 x = in[i * 2], y = in[i * 2 + 1];
  union { __hip_bfloat16 h[8]; int4 v; } u;
  u.h[0] = __float2bfloat16(x.x);
  u.h[1] = __float2bfloat16(x.y);
  u.h[2] = __float2bfloat16(x.z);
  u.h[3] = __float2bfloat16(x.w);
  u.h[4] = __float2bfloat16(y.x);
  u.h[5] = __float2bfloat16(y.y);
  u.h[6] = __float2bfloat16(y.z);
  u.h[7] = __float2bfloat16(y.w);
  out[i] = u.v;
}

__global__ void build_bias(const float* __restrict__ headsb, const float* __restrict__ bc1,
                           float* __restrict__ biasc) {
  const int i = blockIdx.x * blockDim.x + threadIdx.x;
  if (i < 2560) biasc[i] = headsb[i];
  else if (i < 3072) biasc[i] = bc1[i - 2560];
}

__global__ void transpose_to_bf16(const float* __restrict__ in, __hip_bfloat16* __restrict__ out,
                                  int R, int C) {
  __shared__ float t[32][33];
  const int bx = blockIdx.x * 32, by = blockIdx.y * 32;
  in  += (size_t)blockIdx.z * R * C;
  out += (size_t)blockIdx.z * R * C;
  const int x = threadIdx.x, y = threadIdx.y;
#pragma unroll
  for (int i = 0; i < 32; i += 8)
    t[y + i][x] = in[(size_t)(by + y + i) * C + bx + x];
  __syncthreads();
#pragma unroll
  for (int i = 0; i < 32; i += 8)
    out[(size_t)(bx + y + i) * R + by + x] = __float2bfloat16(t[x][y + i]);
}

// ---------------------------------------------------------------------------
// GEMM kernel, template WM = waves along M (2 -> BN=256, 4 -> BN=128)
// BM=256 fixed. 512 thr (8 waves). K-tile = 256xK32 A-region (16KB) +
// BNxK32 B-region (WN*4KB), swizzled subtiles (byte ^= ((b>>9)&1)<<5).
// ---------------------------------------------------------------------------

__device__ __forceinline__ void decode_chunk(int o, int& r, int& cb) {
  const int L = o ^ (((o >> 9) & 1) << 5);
  r  = ((L >> 10) << 4) | ((L >> 6) & 15);
  cb = ((L >> 4) & 3) << 4;
}

template<int WM>
__global__ __launch_bounds__(512, 2)
void gemm_kt(const __hip_bfloat16* __restrict__ A,
             const __hip_bfloat16* __restrict__ Bt,
             const float* __restrict__ bias,
             __hip_bfloat16* __restrict__ C,
             int N, int K, int relu_from, int gx) {
  constexpr int WN   = 8 / WM;          // waves along N
  constexpr int MR   = 16 / WM;         // 16-row m-frags per wave
  constexpr int BREG = WN * 4096;       // B-region bytes per K-tile
  constexpr int TB   = 16384 + BREG;    // K-tile bytes (32KB / 24KB)
  constexpr int NSTG = 2 + WN / 2;      // stage instrs per K-tile (4 / 3)

  __shared__ char smem[4 * TB];

  const int tid  = threadIdx.x;
  const int lane = tid & 63;
  const int wave = tid >> 6;
  const int wr = wave / WN, wc = wave % WN;
  const int lr = lane & 15, ls = lane >> 4;

  // bijective XCD swizzle (grids here are multiples of 8)
  const int nwg = gridDim.x;
  const int q8 = nwg >> 3;
  const int id = (blockIdx.x & 7) * q8 + (blockIdx.x >> 3);
  const int bx = id % gx, by = id / gx;
  const int m0 = by * 256, n0 = bx * (WN * 64);

  // staging source decode (chunk -> row, col-byte within K-tile)
  int rA0, cA0, rA1, cA1, rB0, cB0, rB1, cB1;
  decode_chunk(tid * 16, rA0, cA0);
  decode_chunk(tid * 16 + 8192, rA1, cA1);
  decode_chunk(tid * 16, rB0, cB0);
  decode_chunk(tid * 16 + 8192, rB1, cB1);

  const size_t K2 = (size_t)K * 2;
  const char* pA0 = (const char*)A + (size_t)(m0 + rA0) * K2 + cA0;
  const char* pA1 = (const char*)A + (size_t)(m0 + rA1) * K2 + cA1;
  const char* pB0 = (const char*)Bt + (size_t)(n0 + rB0) * K2 + cB0;
  const char* pB1 = (const char*)Bt + (size_t)(n0 + rB1) * K2 + cB1;  // unused if WN==2

  char* const s0 = smem + (tid << 4);

  // reader lane offset (swizzled), constant
  const int laneOff = lr * 64 + ((ls * 16) ^ ((lr & 8) << 2));

  v4f acc[MR][4] = {};

  // stage helpers: issue NSTG global_load_lds for one K-tile into ring slot
  auto stage_A = [&](int stOff) {
    load_lds16(pA0, s0 + stOff);
    load_lds16(pA1, s0 + stOff + 8192);
    pA0 += 64; pA1 += 64;
  };
  auto stage_B = [&](int stOff) {
    load_lds16(pB0, s0 + stOff + 16384);
    pB0 += 64;
    if constexpr (WN == 4) {
      load_lds16(pB1, s0 + stOff + 24576);
      pB1 += 64;
    }
  };

  // one K-tile: reads + stages + MFMA phases; gate is a callable (vmcnt wait)
  auto tile = [&](int bufOff, int stOff, bool doStage, auto gate) {
    const char* aB = smem + bufOff + wr * (MR * 1024) + laneOff;
    const char* bB = smem + bufOff + 16384 + wc * 4096 + laneOff;
    v8bf af[4], bfr[4];
#pragma unroll
    for (int m = 0; m < 4; ++m) af[m] = *(const v8bf*)(aB + m * 1024);
#pragma unroll
    for (int n = 0; n < 4; ++n) bfr[n] = *(const v8bf*)(bB + n * 1024);
    if (doStage) {
      stage_A(stOff);
      if constexpr (MR == 4) stage_B(stOff);
    }
    BARRIER; WAIT_LGKM0;
    __builtin_amdgcn_s_setprio(1);
#pragma unroll
    for (int m = 0; m < 4; ++m)
#pragma unroll
      for (int n = 0; n < 4; ++n)
        acc[m][n] = __builtin_amdgcn_mfma_f32_16x16x32_bf16(af[m], bfr[n], acc[m][n], 0, 0, 0);
    __builtin_amdgcn_s_setprio(0); SCHEDB;
    if constexpr (MR == 8) {
      BARRIER;
#pragma unroll
      for (int m = 0; m < 4; ++m) af[m] = *(const v8bf*)(aB + (4 + m) * 1024);
      if (doStage) stage_B(stOff);
      BARRIER; WAIT_LGKM0;
      __builtin_amdgcn_s_setprio(1);
#pragma unroll
      for (int m = 0; m < 4; ++m)
#pragma unroll
        for (int n = 0; n < 4; ++n)
          acc[4 + m][n] =
              __builtin_amdgcn_mfma_f32_16x16x32_bf16(af[m], bfr[n], acc[4 + m][n], 0, 0, 0);
      __builtin_amdgcn_s_setprio(0); SCHEDB;
    }
    gate();
    BARRIER;
  };

  // prologue: stage tiles 0,1,2 into ring slots 0,1,2; gate tile0; barrier
  stage_A(0);      stage_B(0);
  stage_A(TB);     stage_B(TB);
  stage_A(2 * TB); stage_B(2 * TB);
  wait_vm<2 * NSTG>();
  BARRIER; SCHEDB;

  const int NT = K >> 5;   // K-tiles (>= 4, K multiple of 32)
  int t = 0;
  for (; t + 3 < NT; ++t)
    tile((t & 3) * TB, ((t + 3) & 3) * TB, true, [] { wait_vm<2 * NSTG>(); });
  tile((t & 3) * TB, 0, false, [] { wait_vm<NSTG>(); }); ++t;
  tile((t & 3) * TB, 0, false, [] { wait_vm<0>(); });    ++t;
  tile((t & 3) * TB, 0, false, [] {});

  // epilogue: C/D layout col=lane&15, row=(lane>>4)*4+reg  [m89-verified]
  const int colb = n0 + wc * 64 + lr;
  const int rowb = m0 + wr * (MR * 16) + ls * 4;
#pragma unroll
  for (int n = 0; n < 4; ++n) {
    const int col = colb + n * 16;
    const float bv = bias[col];
    const bool rl = (col >= relu_from);
#pragma unroll
    for (int m = 0; m < MR; ++m) {
      const int rbase = rowb + m * 16;
#pragma unroll
      for (int j = 0; j < 4; ++j) {
        float v = acc[m][n][j] + bv;
        if (rl) v = fmaxf(v, 0.0f);
        C[(size_t)(rbase + j) * N + col] = __float2bfloat16(v);
      }
    }
  }
}

// ---------------------------------------------------------------------------
// finalize (unchanged, verified): wave per row, 8 segments/pass, vector loads
// ---------------------------------------------------------------------------

__global__ __launch_bounds__(256)
void finalize_kernel(const __hip_bfloat16* __restrict__ out3,
                     const int* __restrict__ masks,
                     const int* __restrict__ actions,
                     const float* __restrict__ Wc2,
                     const float* __restrict__ bc2,
                     float* __restrict__ out) {
  const int lane = threadIdx.x & 63;
  const int r = blockIdx.x * 4 + (threadIdx.x >> 6);
  const __hip_bfloat16* row = out3 + (size_t)r * 3072;
  const int* mrow = masks + (size_t)r * 2560;
  const int* arow = actions + r * 40;

  const int g = lane >> 3;

  float lp_sum = 0.f, ent_sum = 0.f;

#pragma unroll
  for (int p = 0; p < 5; ++p) {
    const int base = p * 512 + lane * 8;
    union { int4 q; __hip_bfloat16 h[8]; } u;
    u.q = *(const int4*)(row + base);
    const int4 ma = *(const int4*)(mrow + base);
    const int4 mb = *(const int4*)(mrow + base + 4);

    float v[8];
    v[0] = ma.x ? __bfloat162float(u.h[0]) : -1.0e9f;
    v[1] = ma.y ? __bfloat162float(u.h[1]) : -1.0e9f;
    v[2] = ma.z ? __bfloat162float(u.h[2]) : -1.0e9f;
    v[3] = ma.w ? __bfloat162float(u.h[3]) : -1.0e9f;
    v[4] = mb.x ? __bfloat162float(u.h[4]) : -1.0e9f;
    v[5] = mb.y ? __bfloat162float(u.h[5]) : -1.0e9f;
    v[6] = mb.z ? __bfloat162float(u.h[6]) : -1.0e9f;
    v[7] = mb.w ? __bfloat162float(u.h[7]) : -1.0e9f;

    float mx = fmaxf(fmaxf(fmaxf(v[0], v[1]), fmaxf(v[2], v[3])),
                     fmaxf(fmaxf(v[4], v[5]), fmaxf(v[6], v[7])));
#pragma unroll
    for (int o = 1; o < 8; o <<= 1) mx = fmaxf(mx, __shfl_xor(mx, o));

    float s = 0.f, sv = 0.f;
#pragma unroll
    for (int j = 0; j < 8; ++j) {
      const float e = __expf(v[j] - mx);
      s += e;
      sv += e * v[j];
    }
#pragma unroll
    for (int o = 1; o < 8; o <<= 1) { s += __shfl_xor(s, o); sv += __shfl_xor(sv, o); }

    const float logZ = __logf(s) + mx;

    const int act = arow[p * 8 + g];
    float va_loc = v[0];
#pragma unroll
    for (int j = 1; j < 8; ++j) va_loc = ((act & 7) == j) ? v[j] : va_loc;
    const float va = __shfl(va_loc, (lane & 56) | ((act >> 3) & 7));

    if ((unsigned)act < 64u) {
      lp_sum += va - logZ;
      ent_sum += logZ - sv / s;
    } else {
      lp_sum += -1000.0f;
    }
  }

#pragma unroll
  for (int o = 8; o < 64; o <<= 1) {
    lp_sum += __shfl_xor(lp_sum, o);
    ent_sum += __shfl_xor(ent_sum, o);
  }

  union { int4 q; __hip_bfloat16 h[8]; } c;
  c.q = *(const int4*)(row + 2560 + lane * 8);
  const float4 w0 = *(const float4*)(Wc2 + lane * 8);
  const float4 w1 = *(const float4*)(Wc2 + lane * 8 + 4);
  float acc = __bfloat162float(c.h[0]) * w0.x + __bfloat162float(c.h[1]) * w0.y +
              __bfloat162float(c.h[2]) * w0.z + __bfloat162float(c.h[3]) * w0.w +
              __bfloat162float(c.h[4]) * w1.x + __bfloat162float(c.h[5]) * w1.y +
              __bfloat162float(c.h[6]) * w1.z + __bfloat162float(c.h[7]) * w1.w;
#pragma unroll
  for (int o = 32; o > 0; o >>= 1) acc += __shfl_xor(acc, o);

  if (lane == 0) {
    out[r]         = lp_sum;
    out[8192 + r]  = ent_sum;
    out[16384 + r] = acc + bc2[0];
  }
}

// ---------------------------------------------------------------------------

extern "C" void kernel_launch(void* const* d_in, const int* in_sizes, int n_in,
                              void* d_out, int out_size, void* d_ws, size_t ws_size,
                              hipStream_t stream) {
  const float* obs    = (const float*)d_in[0];
  const int*   actions= (const int*)d_in[1];
  const int*   masks  = (const int*)d_in[2];
  const float* W1     = (const float*)d_in[3];
  const float* b1     = (const float*)d_in[4];
  const float* W2     = (const float*)d_in[5];
  const float* b2     = (const float*)d_in[6];
  const float* headsW = (const float*)d_in[7];
  const float* headsb = (const float*)d_in[8];
  const float* Wc1    = (const float*)d_in[9];
  const float* bc1    = (const float*)d_in[10];
  const float* Wc2    = (const float*)d_in[11];
  const float* bc2    = (const float*)d_in[12];
  float* out = (float*)d_out;

  char* ws = (char*)d_ws;
  __hip_bfloat16* obsB  = (__hip_bfloat16*)(ws);              // 8192*512*2   = 8388608
  __hip_bfloat16* W1t   = (__hip_bfloat16*)(ws + 8388608);    // 1024*512*2   = 1048576
  __hip_bfloat16* W2t   = (__hip_bfloat16*)(ws + 9437184);    // 1024*1024*2  = 2097152
  __hip_bfloat16* Wbigt = (__hip_bfloat16*)(ws + 11534336);   // 3072*1024*2  = 6291456
  float*          biasc = (float*)(ws + 17825792);            // 3072*4       = 12288
  __hip_bfloat16* h1    = (__hip_bfloat16*)(ws + 17838080);   // 8192*1024*2  = 16777216
  __hip_bfloat16* h2    = (__hip_bfloat16*)(ws + 34615296);   // 8192*1024*2  = 16777216
  __hip_bfloat16* out3  = (__hip_bfloat16*)(ws + 51392512);   // 8192*3072*2  = 50331648

  convert_obs<<<2048, 256, 0, stream>>>((const float4*)obs, (int4*)obsB, 524288);
  build_bias<<<12, 256, 0, stream>>>(headsb, bc1, biasc);
  transpose_to_bf16<<<dim3(32, 16, 1), dim3(32, 8), 0, stream>>>(W1, W1t, 512, 1024);
  transpose_to_bf16<<<dim3(32, 32, 1), dim3(32, 8), 0, stream>>>(W2, W2t, 1024, 1024);
  transpose_to_bf16<<<dim3(10, 32, 8), dim3(32, 8), 0, stream>>>(headsW, Wbigt, 1024, 320);
  transpose_to_bf16<<<dim3(16, 32, 1), dim3(32, 8), 0, stream>>>(Wc1, Wbigt + 2560 * 1024, 1024, 512);

  // G1/G2: 256x128 tiles (WM=4) -> 32x8 = 256 blocks = full machine
  gemm_kt<4><<<dim3(256), 512, 0, stream>>>(obsB, W1t, b1, h1, 1024, 512, 0, 8);
  gemm_kt<4><<<dim3(256), 512, 0, stream>>>(h1, W2t, b2, h2, 1024, 1024, 0, 8);
  // G3: 256x256 tiles (WM=2) -> 32x12 = 384 blocks
  gemm_kt<2><<<dim3(384), 512, 0, stream>>>(h2, Wbigt, biasc, out3, 3072, 1024, 2560, 12);

  finalize_kernel<<<2048, 256, 0, stream>>>(out3, masks, actions, Wc2, bc2, out);
}

// Round 5
// 137.919 us; speedup vs baseline: 1.1584x; 1.0900x over previous
//
#include <hip/hip_runtime.h>
#include <hip/hip_bf16.h>
#include <stdint.h>

// ---------------------------------------------------------------------------
// MaskedPolicy: obs->MLP->heads (masked log-softmax, gather, entropy) + critic
// B=8192 OBS=512 HID=1024 N*SUM=2560 (+512 critic cols = 3072 fused GEMM3)
// GEMM: 128x128 tile, BK=64, 4 waves, double-buffered 64KiB LDS ->
// 2 blocks/CU (decoupled barrier domains), counted vmcnt(8) gate (never 0
// in-loop), lgkmcnt(8) split so MFMA ks0 overlaps ks1 read latency.
// ---------------------------------------------------------------------------

typedef __bf16 v8bf __attribute__((ext_vector_type(8)));
typedef float  v4f  __attribute__((ext_vector_type(4)));

__device__ __forceinline__ void load_lds16(const void* g, void* l) {
  auto gp = (const __attribute__((address_space(1))) char*)(uintptr_t)g;
  auto lp = (__attribute__((address_space(3))) char*)(uintptr_t)l;
  __builtin_amdgcn_global_load_lds(gp, lp, 16, 0, 0);
}

#define BARRIER __builtin_amdgcn_s_barrier()
#define SCHEDB  __builtin_amdgcn_sched_barrier(0)
#define WAIT_LGKM0 do { asm volatile("s_waitcnt lgkmcnt(0)" ::: "memory"); SCHEDB; } while (0)
#define WAIT_LGKM8 do { asm volatile("s_waitcnt lgkmcnt(8)" ::: "memory"); SCHEDB; } while (0)
#define WAIT_VM8   do { asm volatile("s_waitcnt vmcnt(8)" ::: "memory"); SCHEDB; } while (0)
#define WAIT_VM0   do { asm volatile("s_waitcnt vmcnt(0)" ::: "memory"); SCHEDB; } while (0)

// ---------------------------------------------------------------------------
// prep kernels (unchanged, verified)
// ---------------------------------------------------------------------------

__global__ void convert_obs(const float4* __restrict__ in, int4* __restrict__ out, int n8) {
  const int i = blockIdx.x * blockDim.x + threadIdx.x;
  if (i >= n8) return;
  const float4 x = in[i * 2], y = in[i * 2 + 1];
  union { __hip_bfloat16 h[8]; int4 v; } u;
  u.h[0] = __float2bfloat16(x.x);
  u.h[1] = __float2bfloat16(x.y);
  u.h[2] = __float2bfloat16(x.z);
  u.h[3] = __float2bfloat16(x.w);
  u.h[4] = __float2bfloat16(y.x);
  u.h[5] = __float2bfloat16(y.y);
  u.h[6] = __float2bfloat16(y.z);
  u.h[7] = __float2bfloat16(y.w);
  out[i] = u.v;
}

__global__ void build_bias(const float* __restrict__ headsb, const float* __restrict__ bc1,
                           float* __restrict__ biasc) {
  const int i = blockIdx.x * blockDim.x + threadIdx.x;
  if (i < 2560) biasc[i] = headsb[i];
  else if (i < 3072) biasc[i] = bc1[i - 2560];
}

__global__ void transpose_to_bf16(const float* __restrict__ in, __hip_bfloat16* __restrict__ out,
                                  int R, int C) {
  __shared__ float t[32][33];
  const int bx = blockIdx.x * 32, by = blockIdx.y * 32;
  in  += (size_t)blockIdx.z * R * C;
  out += (size_t)blockIdx.z * R * C;
  const int x = threadIdx.x, y = threadIdx.y;
#pragma unroll
  for (int i = 0; i < 32; i += 8)
    t[y + i][x] = in[(size_t)(by + y + i) * C + bx + x];
  __syncthreads();
#pragma unroll
  for (int i = 0; i < 32; i += 8)
    out[(size_t)(bx + y + i) * R + by + x] = __float2bfloat16(t[x][y + i]);
}

// ---------------------------------------------------------------------------
// GEMM: C[M][N] = relu?(A * Bt^T + bias) -> bf16.  BM=BN=128, BK=64.
// LDS buffer (32KB): A_ks0 | A_ks1 | B_ks0 | B_ks1, each 8KB = 8 subtiles of
// [16 rows x 64B], swizzled byte^=((b>>9)&1)<<5 (verified 0-conflict).
// ---------------------------------------------------------------------------

__device__ __forceinline__ void decode_chunk(int o, int& r, int& cb) {
  const int L = o ^ (((o >> 9) & 1) << 5);
  r  = ((L >> 10) << 4) | ((L >> 6) & 15);
  cb = ((L >> 4) & 3) << 4;
}

__global__ __launch_bounds__(256, 2)
void gemm_db(const __hip_bfloat16* __restrict__ A,
             const __hip_bfloat16* __restrict__ Bt,
             const float* __restrict__ bias,
             __hip_bfloat16* __restrict__ C,
             int N, int K, int relu_from, int gx) {
  __shared__ char smem[65536];

  const int tid  = threadIdx.x;
  const int lane = tid & 63;
  const int wave = tid >> 6;
  const int wr = wave >> 1, wc = wave & 1;
  const int lr = lane & 15, ls = lane >> 4;

  // bijective XCD swizzle (all grids are multiples of 8)
  const int nwg = gridDim.x;
  const int q8 = nwg >> 3;
  const int id = (blockIdx.x & 7) * q8 + (blockIdx.x >> 3);
  const int bx = id % gx, by = id / gx;
  const int m0 = by * 128, n0 = bx * 128;

  // staging source decode: this thread owns chunks tid*16 and tid*16+4096 of
  // each 8KB sub-region
  int r0, c0, r1, c1;
  decode_chunk(tid * 16, r0, c0);
  decode_chunk(tid * 16 + 4096, r1, c1);

  const size_t K2 = (size_t)K * 2;
  const char* pA0 = (const char*)A  + (size_t)(m0 + r0) * K2 + c0;
  const char* pA1 = (const char*)A  + (size_t)(m0 + r1) * K2 + c1;
  const char* pB0 = (const char*)Bt + (size_t)(n0 + r0) * K2 + c0;
  const char* pB1 = (const char*)Bt + (size_t)(n0 + r1) * K2 + c1;

  char* const s0 = smem + (tid << 4);

  // stage one K64-tile (8 x global_load_lds) into buffer buf
  auto stage = [&](int buf) {
    char* d = s0 + (buf << 15);
    load_lds16(pA0,      d);              // A ks0
    load_lds16(pA1,      d + 4096);
    load_lds16(pA0 + 64, d + 8192);       // A ks1
    load_lds16(pA1 + 64, d + 12288);
    load_lds16(pB0,      d + 16384);      // B ks0
    load_lds16(pB1,      d + 20480);
    load_lds16(pB0 + 64, d + 24576);      // B ks1
    load_lds16(pB1 + 64, d + 28672);
    pA0 += 128; pA1 += 128; pB0 += 128; pB1 += 128;
  };

  // reader lane offset (swizzled), constant
  const int laneOff = lr * 64 + ((ls * 16) ^ ((lr & 8) << 2));

  v4f acc[4][4] = {};

  // one K64-tile: 16 ds_read, 2x16 MFMA, stage t+2, counted gate
  auto tile = [&](int buf, bool doStage, auto gate) {
    const char* aB = smem + (buf << 15) + wr * 4096 + laneOff;
    const char* bB = smem + (buf << 15) + 16384 + wc * 4096 + laneOff;
    v8bf a0[4], b0[4], a1[4], b1[4];
#pragma unroll
    for (int m = 0; m < 4; ++m) a0[m] = *(const v8bf*)(aB + m * 1024);
#pragma unroll
    for (int n = 0; n < 4; ++n) b0[n] = *(const v8bf*)(bB + n * 1024);
#pragma unroll
    for (int m = 0; m < 4; ++m) a1[m] = *(const v8bf*)(aB + 8192 + m * 1024);
#pragma unroll
    for (int n = 0; n < 4; ++n) b1[n] = *(const v8bf*)(bB + 8192 + n * 1024);
    WAIT_LGKM8;                 // ks0 frags resident
    __builtin_amdgcn_s_setprio(1);
#pragma unroll
    for (int m = 0; m < 4; ++m)
#pragma unroll
      for (int n = 0; n < 4; ++n)
        acc[m][n] = __builtin_amdgcn_mfma_f32_16x16x32_bf16(a0[m], b0[n], acc[m][n], 0, 0, 0);
    __builtin_amdgcn_s_setprio(0); SCHEDB;
    WAIT_LGKM0;                 // all my reads of this buffer retired
    BARRIER;                    // all waves done reading -> safe to overwrite
    if (doStage) stage(buf);    // async DMA for tile t+2 into freed buffer
    __builtin_amdgcn_s_setprio(1);
#pragma unroll
    for (int m = 0; m < 4; ++m)
#pragma unroll
      for (int n = 0; n < 4; ++n)
        acc[m][n] = __builtin_amdgcn_mfma_f32_16x16x32_bf16(a1[m], b1[n], acc[m][n], 0, 0, 0);
    __builtin_amdgcn_s_setprio(0); SCHEDB;
    gate();                     // vmcnt(8): tile t+1 resident (t+2 in flight)
    BARRIER;
  };

  // prologue: stage tiles 0,1; wait tile0; barrier
  stage(0);
  stage(1);
  WAIT_VM8;
  BARRIER; SCHEDB;

  const int NT = K >> 6;        // K64-tiles (K multiple of 64, NT >= 4, even)
  int t = 0;
  for (; t < NT - 2; ++t)
    tile(t & 1, true, [] { WAIT_VM8; });
  tile(t & 1, false, [] { WAIT_VM0; }); ++t;
  tile(t & 1, false, [] {});

  // epilogue: C/D layout col=lane&15, row=(lane>>4)*4+reg  [m89-verified]
  const int colb = n0 + wc * 64 + lr;
  const int rowb = m0 + wr * 64 + ls * 4;
#pragma unroll
  for (int n = 0; n < 4; ++n) {
    const int col = colb + n * 16;
    const float bv = bias[col];
    const bool rl = (col >= relu_from);
#pragma unroll
    for (int m = 0; m < 4; ++m) {
      const int rbase = rowb + m * 16;
#pragma unroll
      for (int j = 0; j < 4; ++j) {
        float v = acc[m][n][j] + bv;
        if (rl) v = fmaxf(v, 0.0f);
        C[(size_t)(rbase + j) * N + col] = __float2bfloat16(v);
      }
    }
  }
}

// ---------------------------------------------------------------------------
// finalize (unchanged, verified): wave per row, 8 segments/pass, vector loads
// ---------------------------------------------------------------------------

__global__ __launch_bounds__(256)
void finalize_kernel(const __hip_bfloat16* __restrict__ out3,
                     const int* __restrict__ masks,
                     const int* __restrict__ actions,
                     const float* __restrict__ Wc2,
                     const float* __restrict__ bc2,
                     float* __restrict__ out) {
  const int lane = threadIdx.x & 63;
  const int r = blockIdx.x * 4 + (threadIdx.x >> 6);
  const __hip_bfloat16* row = out3 + (size_t)r * 3072;
  const int* mrow = masks + (size_t)r * 2560;
  const int* arow = actions + r * 40;

  const int g = lane >> 3;

  float lp_sum = 0.f, ent_sum = 0.f;

#pragma unroll
  for (int p = 0; p < 5; ++p) {
    const int base = p * 512 + lane * 8;
    union { int4 q; __hip_bfloat16 h[8]; } u;
    u.q = *(const int4*)(row + base);
    const int4 ma = *(const int4*)(mrow + base);
    const int4 mb = *(const int4*)(mrow + base + 4);

    float v[8];
    v[0] = ma.x ? __bfloat162float(u.h[0]) : -1.0e9f;
    v[1] = ma.y ? __bfloat162float(u.h[1]) : -1.0e9f;
    v[2] = ma.z ? __bfloat162float(u.h[2]) : -1.0e9f;
    v[3] = ma.w ? __bfloat162float(u.h[3]) : -1.0e9f;
    v[4] = mb.x ? __bfloat162float(u.h[4]) : -1.0e9f;
    v[5] = mb.y ? __bfloat162float(u.h[5]) : -1.0e9f;
    v[6] = mb.z ? __bfloat162float(u.h[6]) : -1.0e9f;
    v[7] = mb.w ? __bfloat162float(u.h[7]) : -1.0e9f;

    float mx = fmaxf(fmaxf(fmaxf(v[0], v[1]), fmaxf(v[2], v[3])),
                     fmaxf(fmaxf(v[4], v[5]), fmaxf(v[6], v[7])));
#pragma unroll
    for (int o = 1; o < 8; o <<= 1) mx = fmaxf(mx, __shfl_xor(mx, o));

    float s = 0.f, sv = 0.f;
#pragma unroll
    for (int j = 0; j < 8; ++j) {
      const float e = __expf(v[j] - mx);
      s += e;
      sv += e * v[j];
    }
#pragma unroll
    for (int o = 1; o < 8; o <<= 1) { s += __shfl_xor(s, o); sv += __shfl_xor(sv, o); }

    const float logZ = __logf(s) + mx;

    const int act = arow[p * 8 + g];
    float va_loc = v[0];
#pragma unroll
    for (int j = 1; j < 8; ++j) va_loc = ((act & 7) == j) ? v[j] : va_loc;
    const float va = __shfl(va_loc, (lane & 56) | ((act >> 3) & 7));

    if ((unsigned)act < 64u) {
      lp_sum += va - logZ;
      ent_sum += logZ - sv / s;
    } else {
      lp_sum += -1000.0f;
    }
  }

#pragma unroll
  for (int o = 8; o < 64; o <<= 1) {
    lp_sum += __shfl_xor(lp_sum, o);
    ent_sum += __shfl_xor(ent_sum, o);
  }

  union { int4 q; __hip_bfloat16 h[8]; } c;
  c.q = *(const int4*)(row + 2560 + lane * 8);
  const float4 w0 = *(const float4*)(Wc2 + lane * 8);
  const float4 w1 = *(const float4*)(Wc2 + lane * 8 + 4);
  float acc = __bfloat162float(c.h[0]) * w0.x + __bfloat162float(c.h[1]) * w0.y +
              __bfloat162float(c.h[2]) * w0.z + __bfloat162float(c.h[3]) * w0.w +
              __bfloat162float(c.h[4]) * w1.x + __bfloat162float(c.h[5]) * w1.y +
              __bfloat162float(c.h[6]) * w1.z + __bfloat162float(c.h[7]) * w1.w;
#pragma unroll
  for (int o = 32; o > 0; o >>= 1) acc += __shfl_xor(acc, o);

  if (lane == 0) {
    out[r]         = lp_sum;
    out[8192 + r]  = ent_sum;
    out[16384 + r] = acc + bc2[0];
  }
}

// ---------------------------------------------------------------------------

extern "C" void kernel_launch(void* const* d_in, const int* in_sizes, int n_in,
                              void* d_out, int out_size, void* d_ws, size_t ws_size,
                              hipStream_t stream) {
  const float* obs    = (const float*)d_in[0];
  const int*   actions= (const int*)d_in[1];
  const int*   masks  = (const int*)d_in[2];
  const float* W1     = (const float*)d_in[3];
  const float* b1     = (const float*)d_in[4];
  const float* W2     = (const float*)d_in[5];
  const float* b2     = (const float*)d_in[6];
  const float* headsW = (const float*)d_in[7];
  const float* headsb = (const float*)d_in[8];
  const float* Wc1    = (const float*)d_in[9];
  const float* bc1    = (const float*)d_in[10];
  const float* Wc2    = (const float*)d_in[11];
  const float* bc2    = (const float*)d_in[12];
  float* out = (float*)d_out;

  char* ws = (char*)d_ws;
  __hip_bfloat16* obsB  = (__hip_bfloat16*)(ws);              // 8192*512*2   = 8388608
  __hip_bfloat16* W1t   = (__hip_bfloat16*)(ws + 8388608);    // 1024*512*2   = 1048576
  __hip_bfloat16* W2t   = (__hip_bfloat16*)(ws + 9437184);    // 1024*1024*2  = 2097152
  __hip_bfloat16* Wbigt = (__hip_bfloat16*)(ws + 11534336);   // 3072*1024*2  = 6291456
  float*          biasc = (float*)(ws + 17825792);            // 3072*4       = 12288
  __hip_bfloat16* h1    = (__hip_bfloat16*)(ws + 17838080);   // 8192*1024*2  = 16777216
  __hip_bfloat16* h2    = (__hip_bfloat16*)(ws + 34615296);   // 8192*1024*2  = 16777216
  __hip_bfloat16* out3  = (__hip_bfloat16*)(ws + 51392512);   // 8192*3072*2  = 50331648

  convert_obs<<<2048, 256, 0, stream>>>((const float4*)obs, (int4*)obsB, 524288);
  build_bias<<<12, 256, 0, stream>>>(headsb, bc1, biasc);
  transpose_to_bf16<<<dim3(32, 16, 1), dim3(32, 8), 0, stream>>>(W1, W1t, 512, 1024);
  transpose_to_bf16<<<dim3(32, 32, 1), dim3(32, 8), 0, stream>>>(W2, W2t, 1024, 1024);
  transpose_to_bf16<<<dim3(10, 32, 8), dim3(32, 8), 0, stream>>>(headsW, Wbigt, 1024, 320);
  transpose_to_bf16<<<dim3(16, 32, 1), dim3(32, 8), 0, stream>>>(Wc1, Wbigt + 2560 * 1024, 1024, 512);

  // 128x128 tiles, 2 blocks/CU. Grids: 64x8=512 (1 full CU-wave x2),
  // 64x24=1536 (3 full CU-waves) -> zero tail.
  gemm_db<<<dim3(512), 256, 0, stream>>>(obsB, W1t, b1, h1, 1024, 512, 0, 8);
  gemm_db<<<dim3(512), 256, 0, stream>>>(h1, W2t, b2, h2, 1024, 1024, 0, 8);
  gemm_db<<<dim3(1536), 256, 0, stream>>>(h2, Wbigt, biasc, out3, 3072, 1024, 2560, 24);

  finalize_kernel<<<2048, 256, 0, stream>>>(out3, masks, actions, Wc2, bc2, out);
}